// Round 1
// baseline (154.977 us; speedup 1.0000x reference)
//
#include <hip/hip_runtime.h>

// Problem constants (from reference)
#define NQ    10
#define DIM   1024        // 2^NQ
#define N_CLS 10
#define NROWS 16384
#define IMG   784

// 4 waves/block, 2 rows/wave -> 8 rows/block, 2048 blocks.
// LDS ref copy = 40 KiB -> 4 blocks/CU co-resident -> 16 waves/CU (vs 8 before).
#define WAVES_PER_BLK 4
#define ROWS_PER_WAVE 2
#define ROWS_PER_BLK  (WAVES_PER_BLK * ROWS_PER_WAVE)

// ---------------------------------------------------------------------------
// Wave64 sum via DPP (classic GCN sequence). Result valid in lane 63.
// Runs entirely on the VALU pipe (no LDS / ds_bpermute traffic).
// update_dpp(old=0, bound_ctrl=1): invalid/masked lanes contribute 0.
// ---------------------------------------------------------------------------
__device__ __forceinline__ float wave64_sum(float x) {
#define DPP_ADD(ctrl, rmask, bmask)                                           \
  x += __int_as_float(__builtin_amdgcn_update_dpp(                            \
      0, __float_as_int(x), ctrl, rmask, bmask, true));
  DPP_ADD(0x111, 0xf, 0xf)  // row_shr:1
  DPP_ADD(0x112, 0xf, 0xf)  // row_shr:2
  DPP_ADD(0x114, 0xf, 0xe)  // row_shr:4
  DPP_ADD(0x118, 0xf, 0xc)  // row_shr:8
  DPP_ADD(0x142, 0xa, 0xf)  // row_bcast:15
  DPP_ADD(0x143, 0xc, 0xf)  // row_bcast:31
#undef DPP_ADD
  return x;  // total in lane 63
}

// ---------------------------------------------------------------------------
// Kernel 1: ref[c][d] = canon[c][d] / ||canon[c]|| for d<784, else 0.
// One block per class.
// ---------------------------------------------------------------------------
__global__ void ref_prep_kernel(const float* __restrict__ canon,
                                float* __restrict__ ref) {
  __shared__ float red[256];
  const int c = blockIdx.x;
  const int t = threadIdx.x;
  const float* src = canon + c * IMG;

  float ss = 0.f;
  for (int d = t; d < IMG; d += 256) {
    float v = src[d];
    ss += v * v;
  }
  red[t] = ss;
  __syncthreads();
  for (int s = 128; s > 0; s >>= 1) {
    if (t < s) red[t] += red[t + s];
    __syncthreads();
  }
  const float inv = 1.0f / sqrtf(red[0]);

  for (int d = t; d < DIM; d += 256) {
    ref[c * DIM + d] = (d < IMG) ? src[d] * inv : 0.f;
  }
}

// ---------------------------------------------------------------------------
// Kernel 2: ref lives in LDS (staged once per block, 40 KiB), so a wave needs
// no 160-VGPR ref fragment -> VGPRs ~90 -> 4 waves/SIMD, 4 blocks/CU.
// Lane i owns columns {256k + 4i .. +3}, k=0..3 of each row it processes.
// z loads stay perfectly coalesced dwordx4 (1 KiB/wave-inst).
// ds_read_b128 at consecutive 16 B/lane is bank-conflict-free.
// ---------------------------------------------------------------------------
__global__ __launch_bounds__(256, 4) void swaptest_kernel(
    const float* __restrict__ zre, const float* __restrict__ zim,
    const float* __restrict__ ref, float* __restrict__ out) {
  __shared__ float lds_ref[N_CLS * DIM];  // 40 KiB

  const int t = threadIdx.x;

  // Stage ref -> LDS: 2560 float4, 10 per thread, coalesced.
  {
    const float4* src = (const float4*)ref;
    float4* dst = (float4*)lds_ref;
#pragma unroll
    for (int i = 0; i < (N_CLS * DIM / 4) / 256; ++i) {
      dst[i * 256 + t] = src[i * 256 + t];
    }
  }
  __syncthreads();

  const int lane = t & 63;
  const int wave = t >> 6;
  const int row0 = blockIdx.x * ROWS_PER_BLK + wave * ROWS_PER_WAVE;

  for (int r = 0; r < ROWS_PER_WAVE; ++r) {
    const int row = row0 + r;
    if (row >= NROWS) break;

    const float4* pre = (const float4*)(zre + (size_t)row * DIM);
    const float4* pim = (const float4*)(zim + (size_t)row * DIM);

    float4 zr[4], zi[4];
#pragma unroll
    for (int k = 0; k < 4; ++k) {
      zr[k] = pre[k * 64 + lane];
      zi[k] = pim[k * 64 + lane];
    }

    float are[N_CLS], aim[N_CLS];
#pragma unroll
    for (int c = 0; c < N_CLS; ++c) {
      are[c] = 0.f;
      aim[c] = 0.f;
    }

    // All 40 ds_read_b128 addresses share one base reg + imm offset
    // (max offset 40944 < 64 KiB ds imm range).
#pragma unroll
    for (int k = 0; k < 4; ++k) {
#pragma unroll
      for (int c = 0; c < N_CLS; ++c) {
        const float4 rv =
            *(const float4*)(&lds_ref[c * DIM + k * 256 + 4 * lane]);
        are[c] += zr[k].x * rv.x + zr[k].y * rv.y + zr[k].z * rv.z +
                  zr[k].w * rv.w;
        aim[c] += zi[k].x * rv.x + zi[k].y * rv.y + zi[k].z * rv.z +
                  zi[k].w * rv.w;
      }
    }

    // 64-lane reduction on the VALU pipe; totals land in lane 63.
#pragma unroll
    for (int c = 0; c < N_CLS; ++c) {
      are[c] = wave64_sum(are[c]);
      aim[c] = wave64_sum(aim[c]);
    }

    if (lane == 63) {
#pragma unroll
      for (int c = 0; c < N_CLS; ++c) {
        out[(size_t)row * N_CLS + c] = are[c] * are[c] + aim[c] * aim[c];
      }
    }
  }
}

// ---------------------------------------------------------------------------
extern "C" void kernel_launch(void* const* d_in, const int* in_sizes, int n_in,
                              void* d_out, int out_size, void* d_ws,
                              size_t ws_size, hipStream_t stream) {
  const float* z_re = (const float*)d_in[0];
  const float* z_im = (const float*)d_in[1];
  const float* canon = (const float*)d_in[2];
  float* out = (float*)d_out;
  float* ref = (float*)d_ws;  // 10 * 1024 * 4 B = 40 KiB

  ref_prep_kernel<<<N_CLS, 256, 0, stream>>>(canon, ref);

  const int nblk = NROWS / ROWS_PER_BLK;  // 2048
  swaptest_kernel<<<nblk, 256, 0, stream>>>(z_re, z_im, ref, out);
}

// Round 2
// 149.292 us; speedup vs baseline: 1.0381x; 1.0381x over previous
//
#include <hip/hip_runtime.h>

// Problem constants (from reference)
#define DIM     1024
#define N_CLS   10
#define NROWS   16384
#define IMG     784

// Only columns [0, 784) of ref are nonzero (zero-padded reference) -> only
// those z columns matter. Pad the working width to 832 cols = 208 float4 so
// 16 sublanes x 13 steps tile it exactly; LDS ref is zero-padded in the tail,
// so the math stays EXACT while we skip 18.6% of z traffic.
#define NF4      196   // float4 per row actually used (784/4)
#define NF4_PAD  208   // 13 * 16
#define NSTEP    13
#define LSTRIDE  208   // float4 stride per class in LDS (33280 B total)

#define ROWS_PER_BLK 16  // 4 waves x 4 rows (one row per 16-lane group)

typedef float f32x4 __attribute__((ext_vector_type(4)));
typedef float f32x2 __attribute__((ext_vector_type(2)));

static __device__ __forceinline__ f32x2 lo2(f32x4 v) {
  return __builtin_shufflevector(v, v, 0, 1);
}
static __device__ __forceinline__ f32x2 hi2(f32x4 v) {
  return __builtin_shufflevector(v, v, 2, 3);
}

// Packed dual-FP32 FMA (the 157 TF path). Compiler never forms this from
// scalar code; non-volatile asm so the scheduler can still move it.
static __device__ __forceinline__ void pk_fma(f32x2& acc, f32x2 a, f32x2 b) {
  asm("v_pk_fma_f32 %0, %1, %2, %0" : "+v"(acc) : "v"(a), "v"(b));
}

// ---------------------------------------------------------------------------
// Wave64 sum via DPP; result valid in lane 63. (Used for the tiny per-block
// canon normalization only.)
// ---------------------------------------------------------------------------
__device__ __forceinline__ float wave64_sum(float x) {
#define DPP_ADD(ctrl, rmask, bmask)                                           \
  x += __int_as_float(__builtin_amdgcn_update_dpp(                            \
      0, __float_as_int(x), ctrl, rmask, bmask, true));
  DPP_ADD(0x111, 0xf, 0xf)  // row_shr:1
  DPP_ADD(0x112, 0xf, 0xf)  // row_shr:2
  DPP_ADD(0x114, 0xf, 0xe)  // row_shr:4
  DPP_ADD(0x118, 0xf, 0xc)  // row_shr:8
  DPP_ADD(0x142, 0xa, 0xf)  // row_bcast:15
  DPP_ADD(0x143, 0xc, 0xf)  // row_bcast:31
#undef DPP_ADD
  return x;  // total in lane 63
}

// Sum within each 16-lane DPP row; result valid in lane 15 of each row.
// 4 DPP-adds instead of 6 for wave64 -> 3x fewer reduce instructions per row.
__device__ __forceinline__ float group16_sum(float x) {
#define DPP_ADD(ctrl)                                                         \
  x += __int_as_float(__builtin_amdgcn_update_dpp(                            \
      0, __float_as_int(x), ctrl, 0xf, 0xf, true));
  DPP_ADD(0x111)  // row_shr:1
  DPP_ADD(0x112)  // row_shr:2
  DPP_ADD(0x114)  // row_shr:4
  DPP_ADD(0x118)  // row_shr:8
#undef DPP_ADD
  return x;
}

// ---------------------------------------------------------------------------
// Single fused kernel: stage canon -> LDS (padded, zero tail), normalize it
// in LDS (replaces the separate ref_prep launch), then swap-test 16 rows per
// block. Lane (g,s): group g owns row row0+g, sublane s owns float4 column
// s+16j. All z loads and ds_reads are one base vaddr + imm offsets.
// ---------------------------------------------------------------------------
__global__ __launch_bounds__(256, 4) void swaptest_kernel(
    const float* __restrict__ zre, const float* __restrict__ zim,
    const float* __restrict__ canon, float* __restrict__ out) {
  __shared__ f32x4 lref[N_CLS * LSTRIDE];  // 33280 B -> 4 blocks/CU

  const int t = threadIdx.x;
  const int lane = t & 63;
  const int wave = t >> 6;

  // ---- stage canon (zero-padding cols >= 784) ----
#pragma unroll
  for (int c = 0; c < N_CLS; ++c) {
    if (t < NF4_PAD) {
      f32x4 v = {0.f, 0.f, 0.f, 0.f};
      if (t < NF4) v = ((const f32x4*)canon)[c * NF4 + t];
      lref[c * LSTRIDE + t] = v;
    }
  }
  __syncthreads();

  // ---- normalize each class in LDS (wave w handles classes w, w+4, w+8) ----
  for (int c = wave; c < N_CLS; c += 4) {
    float ss = 0.f;
    for (int i = lane; i < NF4_PAD; i += 64) {
      f32x4 v = lref[c * LSTRIDE + i];
      ss += v.x * v.x + v.y * v.y + v.z * v.z + v.w * v.w;
    }
    ss = wave64_sum(ss);                       // lane 63
    float inv = __shfl(1.0f / sqrtf(ss), 63);  // broadcast
    for (int i = lane; i < NF4_PAD; i += 64) {
      f32x4 v = lref[c * LSTRIDE + i];
      v.x *= inv; v.y *= inv; v.z *= inv; v.w *= inv;
      lref[c * LSTRIDE + i] = v;
    }
  }
  __syncthreads();

  // ---- swap test ----
  const int s = lane & 15;
  const int g = lane >> 4;
  const int row = blockIdx.x * ROWS_PER_BLK + wave * 4 + g;

  const f32x4* pr = (const f32x4*)(zre + ((size_t)row << 10)) + s;
  const f32x4* pi = (const f32x4*)(zim + ((size_t)row << 10)) + s;

  f32x2 accr[N_CLS], acci[N_CLS];
#pragma unroll
  for (int c = 0; c < N_CLS; ++c) {
    accr[c] = (f32x2){0.f, 0.f};
    acci[c] = (f32x2){0.f, 0.f};
  }

  // Depth-1 register prefetch: loads for step j+1 stay in flight while step j
  // computes (compiler emits counted vmcnt since there is no barrier here).
  f32x4 zr_n = pr[0];
  f32x4 zi_n = pi[0];
#pragma unroll
  for (int j = 0; j < NSTEP; ++j) {
    const f32x4 zr = zr_n;
    const f32x4 zi = zi_n;
    if (j + 1 < NSTEP) {
      zr_n = pr[(j + 1) * 16];  // byte offset (j+1)*256, imm-foldable
      zi_n = pi[(j + 1) * 16];
    }
#pragma unroll
    for (int c = 0; c < N_CLS; ++c) {
      // 4-way broadcast across groups (same address) -> conflict-free.
      const f32x4 rv = lref[c * LSTRIDE + j * 16 + s];
      pk_fma(accr[c], lo2(zr), lo2(rv));
      pk_fma(accr[c], hi2(zr), hi2(rv));
      pk_fma(acci[c], lo2(zi), lo2(rv));
      pk_fma(acci[c], hi2(zi), hi2(rv));
    }
  }

  // 16-lane reductions; totals land in lane 15 of each group.
#pragma unroll
  for (int c = 0; c < N_CLS; ++c) {
    float sr = group16_sum(accr[c].x + accr[c].y);
    float si = group16_sum(acci[c].x + acci[c].y);
    if (s == 15) {
      out[(size_t)row * N_CLS + c] = sr * sr + si * si;
    }
  }
}

// ---------------------------------------------------------------------------
extern "C" void kernel_launch(void* const* d_in, const int* in_sizes, int n_in,
                              void* d_out, int out_size, void* d_ws,
                              size_t ws_size, hipStream_t stream) {
  const float* z_re = (const float*)d_in[0];
  const float* z_im = (const float*)d_in[1];
  const float* canon = (const float*)d_in[2];
  float* out = (float*)d_out;
  (void)d_ws; (void)ws_size;

  const int nblk = NROWS / ROWS_PER_BLK;  // 1024 blocks = 4/CU, one clean round
  swaptest_kernel<<<nblk, 256, 0, stream>>>(z_re, z_im, canon, out);
}